// Round 1
// baseline (2904.144 us; speedup 1.0000x reference)
//
#include <hip/hip_runtime.h>
#include <hip/hip_fp16.h>

// Problem constants: B=2,G=1024,S=64,L=16,F=8 -> LF=128, ATT=128, RANK=32, HC=32, NH=4
#define NWIN 2048

// ws layout (floats)
#define WS_WQUT   0        // [32][128]  Wq_u^T
#define WS_WKVUT  4096     // [32][128]  Wkv_u^T
#define WS_M      8192     // [4][32][32]  M[h][u][r] = (Wq_v_h Wkv_v_kh^T)/sqrt(32)
#define WS_O      12288    // [4][32][128] O[h][r][j] = Wkv_v_vh Wo_u_h Wo_v
#define WS_CVEC   28672    // [128]  vbias @ Wo_u @ Wo_v
#define WS_CSQU   28800    // [32]   colsum Wq_u
#define WS_CSKVU  28832    // [32]   colsum Wkv_u
#define WS_CSW1   28864    // [128]  colsum W1
#define WS_TOTAL  28992

__global__ __launch_bounds__(256) void fam_precomp(
    const float* __restrict__ Wq_u, const float* __restrict__ Wq_v,
    const float* __restrict__ Wkv_u, const float* __restrict__ Wkv_v,
    const float* __restrict__ kv_b, const float* __restrict__ Wo_u,
    const float* __restrict__ Wo_v, const float* __restrict__ W1,
    float* __restrict__ ws)
{
    __shared__ float Nsh[4096];   // Nsh[h][u][r] holds N[h][r][u] = Wkv_v_vh Wo_u_h
    __shared__ float ovec[32];
    const int tid = threadIdx.x;

    for (int idx = tid; idx < 4096; idx += 256) {
        int i = idx >> 5, r = idx & 31;
        ws[WS_WQUT  + r*128 + i] = Wq_u[i*32 + r];
        ws[WS_WKVUT + r*128 + i] = Wkv_u[i*32 + r];
    }
    if (tid < 32) {
        float a = 0.f, b = 0.f;
        for (int i = 0; i < 128; ++i) { a += Wq_u[i*32 + tid]; b += Wkv_u[i*32 + tid]; }
        ws[WS_CSQU + tid] = a; ws[WS_CSKVU + tid] = b;
        float o = 0.f;
        for (int att = 0; att < 128; ++att) o += kv_b[128 + att] * Wo_u[att*32 + tid];
        ovec[tid] = o;
    }
    if (tid < 128) {
        float a = 0.f;
        for (int k = 0; k < 128; ++k) a += W1[k*128 + tid];
        ws[WS_CSW1 + tid] = a;
    }
    const float sc = 0.17677669529663687f;  // 1/sqrt(32)
    for (int idx = tid; idx < 4096; idx += 256) {
        int h = idx >> 10, u = (idx >> 5) & 31, r = idx & 31;
        float m = 0.f, n = 0.f;
        for (int c = 0; c < 32; ++c) {
            m += Wq_v[u*128 + h*32 + c] * Wkv_v[r*256 + h*32 + c];
            n += Wkv_v[r*256 + 128 + h*32 + c] * Wo_u[(h*32 + c)*32 + u];
        }
        ws[WS_M + idx] = m * sc;
        Nsh[idx] = n;
    }
    __syncthreads();
    for (int idx = tid; idx < 16384; idx += 256) {
        int h = idx >> 12, r = (idx >> 7) & 31, j = idx & 127;
        float o = 0.f;
        for (int u = 0; u < 32; ++u) o += Nsh[h*1024 + u*32 + r] * Wo_v[u*128 + j];
        ws[WS_O + idx] = o;
    }
    if (tid < 128) {
        float cv = 0.f;
        for (int u = 0; u < 32; ++u) cv += ovec[u] * Wo_v[u*128 + tid];
        ws[WS_CVEC + tid] = cv;
    }
}

__global__ __launch_bounds__(256) void fam_main(
    const float* __restrict__ x, const float* __restrict__ ws,
    const float* __restrict__ gamma, const float* __restrict__ W1,
    const float* __restrict__ b1, const float* __restrict__ W2,
    const float* __restrict__ b2, const float* __restrict__ gmlp_p,
    float* __restrict__ out)
{
    __shared__ float xbuf[64][132];   // x -> x1 in place; +4 pad: conflict-light, float4-aligned
    __shared__ float hu[4608];        // hu_q[64][36] | hu_kv[64][36]; later half pu[4][64][36]; later half t1[64][132]
    __shared__ float stats[64][2];    // mean, rinv (reused for LN2)

    const int tid  = threadIdx.x;
    const int wave = tid >> 6;
    const int lane = tid & 63;
    const float* __restrict__ xw   = x   + (size_t)blockIdx.x * 8192;
    float* __restrict__        outw = out + (size_t)blockIdx.x * 8192;

    // ---- load x (coalesced float4) ----
    {
        const float4* __restrict__ x4 = (const float4*)xw;
        #pragma unroll
        for (int k = 0; k < 8; ++k) {
            int idx = k*256 + tid;           // float4 index 0..2047
            float4 v = x4[idx];
            int s = idx >> 5, j = (idx & 31) * 4;
            *(float4*)&xbuf[s][j] = v;
        }
    }
    __syncthreads();

    // ---- LN1 stats (4 threads per row) ----
    {
        int s = tid >> 2, c = tid & 3;
        float sum = 0.f, sq = 0.f;
        #pragma unroll
        for (int j = 0; j < 32; ++j) {
            float v = xbuf[s][c*32 + j];
            sum += v; sq += v*v;
        }
        sum += __shfl_xor(sum, 1); sq += __shfl_xor(sq, 1);
        sum += __shfl_xor(sum, 2); sq += __shfl_xor(sq, 2);
        float mean = sum * (1.f/128.f);
        float var  = sq  * (1.f/128.f) - mean*mean;
        if (c == 0) { stats[s][0] = mean; stats[s][1] = rsqrtf(var + 1e-5f); }
    }
    __syncthreads();

    // ---- hu_q = LN(x)@Wq_u , hu_kv = LN(x)@Wkv_u   (LN folded via colsums) ----
    {
        int r = tid & 31, g = tid >> 5;   // each thread: 1 rank-col, 8 rows
        int s0 = g * 8;
        float accq[8], acck[8];
        #pragma unroll
        for (int j = 0; j < 8; ++j) { accq[j] = 0.f; acck[j] = 0.f; }
        for (int i4 = 0; i4 < 32; ++i4) {
            float4 wq = *(const float4*)&ws[WS_WQUT  + r*128 + i4*4];
            float4 wk = *(const float4*)&ws[WS_WKVUT + r*128 + i4*4];
            #pragma unroll
            for (int j = 0; j < 8; ++j) {
                float4 xv = *(const float4*)&xbuf[s0 + j][i4*4];
                accq[j] += xv.x*wq.x + xv.y*wq.y + xv.z*wq.z + xv.w*wq.w;
                acck[j] += xv.x*wk.x + xv.y*wk.y + xv.z*wk.z + xv.w*wk.w;
            }
        }
        float csq = ws[WS_CSQU + r], csk = ws[WS_CSKVU + r];
        #pragma unroll
        for (int j = 0; j < 8; ++j) {
            int s = s0 + j;
            float mean = stats[s][0], rinv = stats[s][1];
            hu[       s*36 + r] = rinv*accq[j] - rinv*mean*csq;
            hu[2304 + s*36 + r] = rinv*acck[j] - rinv*mean*csk;
        }
    }
    __syncthreads();

    // ---- attention: wave = head, lane = token row; factorized, two-pass softmax ----
    float pu[32];
    {
        const int h = wave, s = lane;
        float qt[32];
        #pragma unroll
        for (int r = 0; r < 32; ++r) qt[r] = 0.f;
        for (int u = 0; u < 32; ++u) {
            float a = hu[s*36 + u];
            #pragma unroll
            for (int r4 = 0; r4 < 8; ++r4) {
                float4 m4 = *(const float4*)&ws[WS_M + h*1024 + u*32 + r4*4];
                qt[r4*4+0] += a*m4.x; qt[r4*4+1] += a*m4.y;
                qt[r4*4+2] += a*m4.z; qt[r4*4+3] += a*m4.w;
            }
        }
        // pass 1: row max
        float mx = -1e30f;
        for (int t = 0; t < 64; ++t) {
            float acc = 0.f;
            #pragma unroll
            for (int r4 = 0; r4 < 8; ++r4) {
                float4 kv = *(const float4*)&hu[2304 + t*36 + r4*4];
                acc += qt[r4*4+0]*kv.x + qt[r4*4+1]*kv.y + qt[r4*4+2]*kv.z + qt[r4*4+3]*kv.w;
            }
            mx = fmaxf(mx, acc);
        }
        // pass 2: exp-weighted accumulate pu = softmax(scores) @ hu_kv
        float ssum = 0.f;
        #pragma unroll
        for (int r = 0; r < 32; ++r) pu[r] = 0.f;
        for (int t = 0; t < 64; ++t) {
            float4 kv0 = *(const float4*)&hu[2304 + t*36 +  0];
            float4 kv1 = *(const float4*)&hu[2304 + t*36 +  4];
            float4 kv2 = *(const float4*)&hu[2304 + t*36 +  8];
            float4 kv3 = *(const float4*)&hu[2304 + t*36 + 12];
            float4 kv4 = *(const float4*)&hu[2304 + t*36 + 16];
            float4 kv5 = *(const float4*)&hu[2304 + t*36 + 20];
            float4 kv6 = *(const float4*)&hu[2304 + t*36 + 24];
            float4 kv7 = *(const float4*)&hu[2304 + t*36 + 28];
            float acc = qt[0]*kv0.x + qt[1]*kv0.y + qt[2]*kv0.z + qt[3]*kv0.w
                      + qt[4]*kv1.x + qt[5]*kv1.y + qt[6]*kv1.z + qt[7]*kv1.w
                      + qt[8]*kv2.x + qt[9]*kv2.y + qt[10]*kv2.z + qt[11]*kv2.w
                      + qt[12]*kv3.x + qt[13]*kv3.y + qt[14]*kv3.z + qt[15]*kv3.w
                      + qt[16]*kv4.x + qt[17]*kv4.y + qt[18]*kv4.z + qt[19]*kv4.w
                      + qt[20]*kv5.x + qt[21]*kv5.y + qt[22]*kv5.z + qt[23]*kv5.w
                      + qt[24]*kv6.x + qt[25]*kv6.y + qt[26]*kv6.z + qt[27]*kv6.w
                      + qt[28]*kv7.x + qt[29]*kv7.y + qt[30]*kv7.z + qt[31]*kv7.w;
            float e = __expf(acc - mx);
            ssum += e;
            pu[0]  += e*kv0.x; pu[1]  += e*kv0.y; pu[2]  += e*kv0.z; pu[3]  += e*kv0.w;
            pu[4]  += e*kv1.x; pu[5]  += e*kv1.y; pu[6]  += e*kv1.z; pu[7]  += e*kv1.w;
            pu[8]  += e*kv2.x; pu[9]  += e*kv2.y; pu[10] += e*kv2.z; pu[11] += e*kv2.w;
            pu[12] += e*kv3.x; pu[13] += e*kv3.y; pu[14] += e*kv3.z; pu[15] += e*kv3.w;
            pu[16] += e*kv4.x; pu[17] += e*kv4.y; pu[18] += e*kv4.z; pu[19] += e*kv4.w;
            pu[20] += e*kv5.x; pu[21] += e*kv5.y; pu[22] += e*kv5.z; pu[23] += e*kv5.w;
            pu[24] += e*kv6.x; pu[25] += e*kv6.y; pu[26] += e*kv6.z; pu[27] += e*kv6.w;
            pu[28] += e*kv7.x; pu[29] += e*kv7.y; pu[30] += e*kv7.z; pu[31] += e*kv7.w;
        }
        float rs = 1.f / ssum;
        #pragma unroll
        for (int r = 0; r < 32; ++r) pu[r] *= rs;
    }
    __syncthreads();                 // all waves done reading hu_q/hu_kv
    {
        __half2* puh = (__half2*)hu; // pu_all[4][64][18] half2 (exactly fills hu region)
        const int h = wave, s = lane;
        #pragma unroll
        for (int rq = 0; rq < 16; ++rq)
            puh[h*1152 + s*18 + rq] = __floats2half2_rn(pu[2*rq], pu[2*rq+1]);
    }
    __syncthreads();

    // ---- upd = sum_h pu_h @ O_h + cvec ; x1 = x + gamma*upd (in place) ----
    {
        const __half2* __restrict__ puh = (const __half2*)hu;
        int s = tid >> 2, j0 = (tid & 3) * 32;
        float acc[32];
        #pragma unroll
        for (int j4 = 0; j4 < 8; ++j4) {
            float4 cv = *(const float4*)&ws[WS_CVEC + j0 + j4*4];
            acc[j4*4+0] = cv.x; acc[j4*4+1] = cv.y; acc[j4*4+2] = cv.z; acc[j4*4+3] = cv.w;
        }
        for (int h = 0; h < 4; ++h) {
            for (int rq = 0; rq < 16; ++rq) {
                float2 a2 = __half22float2(puh[h*1152 + s*18 + rq]);
                const float* O0 = &ws[WS_O + h*4096 + (2*rq)*128 + j0];
                #pragma unroll
                for (int j4 = 0; j4 < 8; ++j4) {
                    float4 o0 = *(const float4*)&O0[j4*4];
                    float4 o1 = *(const float4*)&O0[128 + j4*4];
                    acc[j4*4+0] += a2.x*o0.x + a2.y*o1.x;
                    acc[j4*4+1] += a2.x*o0.y + a2.y*o1.y;
                    acc[j4*4+2] += a2.x*o0.z + a2.y*o1.z;
                    acc[j4*4+3] += a2.x*o0.w + a2.y*o1.w;
                }
            }
        }
        #pragma unroll
        for (int j4 = 0; j4 < 8; ++j4) {
            float4 gm4 = *(const float4*)&gamma[j0 + j4*4];
            xbuf[s][j0 + j4*4 + 0] += gm4.x * acc[j4*4+0];
            xbuf[s][j0 + j4*4 + 1] += gm4.y * acc[j4*4+1];
            xbuf[s][j0 + j4*4 + 2] += gm4.z * acc[j4*4+2];
            xbuf[s][j0 + j4*4 + 3] += gm4.w * acc[j4*4+3];
        }
    }
    __syncthreads();

    // ---- LN2 stats ----
    {
        int s = tid >> 2, c = tid & 3;
        float sum = 0.f, sq = 0.f;
        #pragma unroll
        for (int j = 0; j < 32; ++j) {
            float v = xbuf[s][c*32 + j];
            sum += v; sq += v*v;
        }
        sum += __shfl_xor(sum, 1); sq += __shfl_xor(sq, 1);
        sum += __shfl_xor(sum, 2); sq += __shfl_xor(sq, 2);
        float mean = sum * (1.f/128.f);
        float var  = sq  * (1.f/128.f) - mean*mean;
        if (c == 0) { stats[s][0] = mean; stats[s][1] = rsqrtf(var + 1e-5f); }
    }
    __syncthreads();

    // ---- t1 = gelu(LN(x1)@W1 + b1)  (LN folded; fp16 in reused hu region) ----
    {
        __half* __restrict__ t1 = (__half*)hu;   // [64][132]
        int s = tid >> 2, i0 = (tid & 3) * 32;
        float acc[32];
        #pragma unroll
        for (int i = 0; i < 32; ++i) acc[i] = 0.f;
        for (int k = 0; k < 128; ++k) {
            float xv = xbuf[s][k];
            #pragma unroll
            for (int i4 = 0; i4 < 8; ++i4) {
                float4 w4 = *(const float4*)&W1[k*128 + i0 + i4*4];
                acc[i4*4+0] += xv*w4.x; acc[i4*4+1] += xv*w4.y;
                acc[i4*4+2] += xv*w4.z; acc[i4*4+3] += xv*w4.w;
            }
        }
        float mean = stats[s][0], rinv = stats[s][1];
        float rm = rinv * mean;
        #pragma unroll
        for (int i = 0; i < 32; ++i) {
            float t = rinv*acc[i] - rm*ws[WS_CSW1 + i0 + i] + b1[i0 + i];
            float u = 0.7978845608028654f * (t + 0.044715f*t*t*t);
            u = fminf(fmaxf(u, -15.f), 15.f);
            float e = __expf(2.f*u);
            float th = (e - 1.f) / (e + 1.f);
            t1[s*132 + i0 + i] = __float2half(0.5f*t*(1.f + th));
        }
    }
    __syncthreads();

    // ---- m = t1@W2 + b2 ; out = x1 + gmlp*m ----
    {
        const __half* __restrict__ t1 = (const __half*)hu;
        const float gm = gmlp_p[0];
        int s = tid >> 2, j0 = (tid & 3) * 32;
        float acc[32];
        #pragma unroll
        for (int j = 0; j < 32; ++j) acc[j] = 0.f;
        for (int k = 0; k < 128; ++k) {
            float tv = __half2float(t1[s*132 + k]);
            #pragma unroll
            for (int j4 = 0; j4 < 8; ++j4) {
                float4 w4 = *(const float4*)&W2[k*128 + j0 + j4*4];
                acc[j4*4+0] += tv*w4.x; acc[j4*4+1] += tv*w4.y;
                acc[j4*4+2] += tv*w4.z; acc[j4*4+3] += tv*w4.w;
            }
        }
        #pragma unroll
        for (int j4 = 0; j4 < 8; ++j4) {
            float4 b4 = *(const float4*)&b2[j0 + j4*4];
            float4 r;
            r.x = xbuf[s][j0 + j4*4 + 0] + gm*(acc[j4*4+0] + b4.x);
            r.y = xbuf[s][j0 + j4*4 + 1] + gm*(acc[j4*4+1] + b4.y);
            r.z = xbuf[s][j0 + j4*4 + 2] + gm*(acc[j4*4+2] + b4.z);
            r.w = xbuf[s][j0 + j4*4 + 3] + gm*(acc[j4*4+3] + b4.w);
            *(float4*)&outw[s*128 + j0 + j4*4] = r;
        }
    }
}

extern "C" void kernel_launch(void* const* d_in, const int* in_sizes, int n_in,
                              void* d_out, int out_size, void* d_ws, size_t ws_size,
                              hipStream_t stream) {
    const float* x     = (const float*)d_in[0];
    const float* Wq_u  = (const float*)d_in[1];
    const float* Wq_v  = (const float*)d_in[2];
    const float* Wkv_u = (const float*)d_in[3];
    const float* Wkv_v = (const float*)d_in[4];
    const float* kv_b  = (const float*)d_in[5];
    const float* Wo_u  = (const float*)d_in[6];
    const float* Wo_v  = (const float*)d_in[7];
    const float* gamma = (const float*)d_in[8];
    const float* W1    = (const float*)d_in[9];
    const float* b1    = (const float*)d_in[10];
    const float* W2    = (const float*)d_in[11];
    const float* b2    = (const float*)d_in[12];
    const float* gmlp  = (const float*)d_in[13];
    float* ws  = (float*)d_ws;
    float* out = (float*)d_out;

    fam_precomp<<<1, 256, 0, stream>>>(Wq_u, Wq_v, Wkv_u, Wkv_v, kv_b, Wo_u, Wo_v, W1, ws);
    fam_main<<<NWIN, 256, 0, stream>>>(x, ws, gamma, W1, b1, W2, b2, gmlp, out);
}

// Round 2
// 129.132 us; speedup vs baseline: 22.4898x; 22.4898x over previous
//
#include <hip/hip_runtime.h>

// B=2,G=1024,S=64,L=16,F=8 -> LF=128, ATT=128, RANK=32, HC=32, NH=4. NWIN=2048.
#define NWIN 2048

// ws layout (shorts = bf16), then cvec (float) at byte 122880
#define WUT_OFF 0        // [64][128]  B^T for [hu_q|hu_kv] = [Wq_u|Wkv_u] transposed
#define MT_OFF  8192     // [4][32][32] MT[h][r][u] = M[h][u][r]/sqrt(32)
#define OT_OFF  12288    // [128][128]  OT[j][h*32+r]
#define W1T_OFF 28672    // [128][128]  W1T[i][k] = W1[k][i]
#define W2T_OFF 45056    // [128][128]  W2T[j][k] = W2[k][j]
#define CVEC_BYTE 122880

typedef __attribute__((ext_vector_type(8))) __bf16 bf16x8;
typedef __attribute__((ext_vector_type(8))) short s16x8;
typedef __attribute__((ext_vector_type(4))) short s16x4;
typedef __attribute__((ext_vector_type(4))) float f32x4;

static __device__ inline short f2bf(float f) {
    unsigned u = __builtin_bit_cast(unsigned, f);
    u += 0x7FFFu + ((u >> 16) & 1u);
    return (short)(u >> 16);
}
static __device__ inline bf16x8 ldbf8(const short* p) {
    return __builtin_bit_cast(bf16x8, *(const s16x8*)p);
}

// ---------------- precompute: build bf16 B^T tables in ws ----------------
__global__ __launch_bounds__(256) void fam_pre(
    const float* __restrict__ Wq_u, const float* __restrict__ Wq_v,
    const float* __restrict__ Wkv_u, const float* __restrict__ Wkv_v,
    const float* __restrict__ kv_b, const float* __restrict__ Wo_u,
    const float* __restrict__ Wo_v, const float* __restrict__ W1,
    const float* __restrict__ W2, short* __restrict__ wsS, float* __restrict__ cvec)
{
    const int b = blockIdx.x, tid = threadIdx.x;
    if (b < 16) {
        // OT rows j in [b*8, b*8+8)
        __shared__ float Wv[4096];   // Wkv_v v-part [r][c]  (32x128)
        __shared__ float Wu[4096];   // Wo_u [att][u]        (128x32)
        __shared__ float N[4096];    // N[h][u][r]
        for (int i = tid; i < 4096; i += 256) {
            int r = i >> 7, c = i & 127;
            Wv[i] = Wkv_v[r*256 + 128 + c];
            Wu[i] = Wo_u[i];
        }
        __syncthreads();
        for (int i = tid; i < 4096; i += 256) {
            int h = i >> 10, u = (i >> 5) & 31, r = i & 31;
            float acc = 0.f;
            for (int c = 0; c < 32; ++c) acc += Wv[r*128 + h*32 + c] * Wu[(h*32 + c)*32 + u];
            N[i] = acc;
        }
        __syncthreads();
        for (int i = tid; i < 1024; i += 256) {
            int jj = i >> 7, hr = i & 127;
            int j = b*8 + jj, h = hr >> 5, r = hr & 31;
            float acc = 0.f;
            for (int u = 0; u < 32; ++u) acc += N[h*1024 + u*32 + r] * Wo_v[u*128 + j];
            wsS[OT_OFF + j*128 + hr] = f2bf(acc);
        }
    } else if (b < 32) {
        int i0 = (b - 16) * 8;
        for (int t = tid; t < 1024; t += 256) {
            int ii = t >> 7, k = t & 127, i = i0 + ii;
            wsS[W1T_OFF + i*128 + k] = f2bf(W1[k*128 + i]);
        }
    } else if (b < 48) {
        int j0 = (b - 32) * 8;
        for (int t = tid; t < 1024; t += 256) {
            int jj = t >> 7, k = t & 127, j = j0 + jj;
            wsS[W2T_OFF + j*128 + k] = f2bf(W2[k*128 + j]);
        }
    } else {
        __shared__ float Aq[4096];   // Wq_v [u][128]
        __shared__ float Ak[4096];   // Wkv_v k-part [r][c]
        __shared__ float ov[32];
        for (int i = tid; i < 4096; i += 256) {
            int r = i >> 7, c = i & 127;
            Aq[i] = Wq_v[i];
            Ak[i] = Wkv_v[r*256 + c];
        }
        for (int i = tid; i < 8192; i += 256) {
            int n = i >> 7, k = i & 127;
            wsS[WUT_OFF + i] = f2bf(n < 32 ? Wq_u[k*32 + n] : Wkv_u[k*32 + (n - 32)]);
        }
        __syncthreads();
        const float sc = 0.17677669529663687f;  // 1/sqrt(32)
        for (int i = tid; i < 4096; i += 256) {
            int h = i >> 10, r = (i >> 5) & 31, u = i & 31;
            float acc = 0.f;
            for (int c = 0; c < 32; ++c) acc += Aq[u*128 + h*32 + c] * Ak[r*128 + h*32 + c];
            wsS[MT_OFF + h*1024 + r*32 + u] = f2bf(acc * sc);
        }
        if (tid < 32) {
            float a = 0.f;
            for (int att = 0; att < 128; ++att) a += kv_b[128 + att] * Wo_u[att*32 + tid];
            ov[tid] = a;
        }
        __syncthreads();
        if (tid < 128) {
            float a = 0.f;
            for (int u = 0; u < 32; ++u) a += ov[u] * Wo_v[u*128 + tid];
            cvec[tid] = a;
        }
    }
}

// ---------------- main fused kernel: 1 block = 1 window, 4 waves ----------------
#define LDA 136   // RA row stride (shorts): 272B rows -> 2-way LDS alias (free)
#define LDH 40    // HUQ/HUKV row stride: 80B
#define LDT 72    // HUKVT/PB row stride: 144B

__global__ __launch_bounds__(256, 2) void fam_main(
    const float* __restrict__ x, const short* __restrict__ wsS,
    const float* __restrict__ cvec, const float* __restrict__ gamma,
    const float* __restrict__ b1, const float* __restrict__ b2,
    const float* __restrict__ gmlp_p, float* __restrict__ out)
{
    __shared__ short RA[64 * LDA];      // h -> pu_cat -> h2 -> t1
    __shared__ short HUQ[64 * LDH];     // hu_q [s][r]
    __shared__ short HUKV[64 * LDH];    // hu_kv [t][r]
    __shared__ short HUKVT[32 * LDT];   // hu_kv^T [r][t]
    __shared__ short PB[4][64 * LDT];   // per head: qt [s][u<32], then P [s][t]

    const int tid = threadIdx.x;
    const int l   = tid & 63;
    const int wv  = tid >> 6;
    const int l15 = l & 15;
    const int lg  = l >> 4;
    const size_t base = (size_t)blockIdx.x * 8192;
    const float* __restrict__ xw   = x + base;
    float* __restrict__       outw = out + base;

    // ---- P1: LN1 -> h (bf16) in RA ----
    {
        int s = tid >> 2, c = tid & 3;
        float4 xr[8];
        float sum = 0.f, sq = 0.f;
        #pragma unroll
        for (int j = 0; j < 8; ++j) {
            xr[j] = *(const float4*)&xw[s*128 + c*32 + j*4];
            sum += xr[j].x + xr[j].y + xr[j].z + xr[j].w;
            sq  += xr[j].x*xr[j].x + xr[j].y*xr[j].y + xr[j].z*xr[j].z + xr[j].w*xr[j].w;
        }
        sum += __shfl_xor(sum, 1); sq += __shfl_xor(sq, 1);
        sum += __shfl_xor(sum, 2); sq += __shfl_xor(sq, 2);
        float mean = sum * (1.f/128.f);
        float var  = sq * (1.f/128.f) - mean*mean;
        float rinv = rsqrtf(var + 1e-5f);
        #pragma unroll
        for (int j = 0; j < 8; ++j) {
            s16x4 hv;
            hv.x = f2bf((xr[j].x - mean) * rinv);
            hv.y = f2bf((xr[j].y - mean) * rinv);
            hv.z = f2bf((xr[j].z - mean) * rinv);
            hv.w = f2bf((xr[j].w - mean) * rinv);
            *(s16x4*)&RA[s*LDA + c*32 + j*4] = hv;
        }
    }
    __syncthreads();

    // ---- P2: [hu_q|hu_kv] = h @ [Wq_u|Wkv_u]; wave = 16-col strip ----
    {
        const int n = wv;
        const short* Bt = wsS + WUT_OFF;
        bf16x8 bfr[4];
        #pragma unroll
        for (int k = 0; k < 4; ++k)
            bfr[k] = ldbf8(&Bt[(n*16 + l15)*128 + k*32 + lg*8]);
        #pragma unroll
        for (int m = 0; m < 4; ++m) {
            f32x4 acc = {0.f, 0.f, 0.f, 0.f};
            #pragma unroll
            for (int k = 0; k < 4; ++k) {
                bf16x8 a = ldbf8(&RA[(m*16 + l15)*LDA + k*32 + lg*8]);
                acc = __builtin_amdgcn_mfma_f32_16x16x32_bf16(a, bfr[k], acc, 0, 0, 0);
            }
            int col = n*16 + l15;
            #pragma unroll
            for (int j = 0; j < 4; ++j) {
                int row = m*16 + lg*4 + j;
                short v = f2bf(acc[j]);
                if (n < 2) {
                    HUQ[row*LDH + col] = v;
                } else {
                    HUKV[row*LDH + (col - 32)] = v;
                    HUKVT[(col - 32)*LDT + row] = v;
                }
            }
        }
    }
    __syncthreads();

    // ---- P3: qt_h = hu_q @ M_h  (wave = head) ----
    {
        const int h = wv;
        const short* Mt = wsS + MT_OFF + h*1024;
        bf16x8 bm[2];
        #pragma unroll
        for (int nn = 0; nn < 2; ++nn)
            bm[nn] = ldbf8(&Mt[(nn*16 + l15)*32 + lg*8]);
        #pragma unroll
        for (int m = 0; m < 4; ++m) {
            bf16x8 a = ldbf8(&HUQ[(m*16 + l15)*LDH + lg*8]);
            #pragma unroll
            for (int nn = 0; nn < 2; ++nn) {
                f32x4 acc = {0.f, 0.f, 0.f, 0.f};
                acc = __builtin_amdgcn_mfma_f32_16x16x32_bf16(a, bm[nn], acc, 0, 0, 0);
                #pragma unroll
                for (int j = 0; j < 4; ++j)
                    PB[h][(m*16 + lg*4 + j)*LDT + nn*16 + l15] = f2bf(acc[j]);
            }
        }
    }

    // ---- P4: scores_h = qt_h @ hu_kv^T ; softmax in C-registers; P -> PB[h] ----
    {
        const int h = wv;
        f32x4 cc[4][4];
        bf16x8 bk[4];
        #pragma unroll
        for (int n = 0; n < 4; ++n)
            bk[n] = ldbf8(&HUKV[(n*16 + l15)*LDH + lg*8]);
        #pragma unroll
        for (int m = 0; m < 4; ++m) {
            bf16x8 a = ldbf8(&PB[h][(m*16 + l15)*LDT + lg*8]);
            #pragma unroll
            for (int n = 0; n < 4; ++n) {
                f32x4 z = {0.f, 0.f, 0.f, 0.f};
                cc[m][n] = __builtin_amdgcn_mfma_f32_16x16x32_bf16(a, bk[n], z, 0, 0, 0);
            }
        }
        #pragma unroll
        for (int m = 0; m < 4; ++m) {
            #pragma unroll
            for (int j = 0; j < 4; ++j) {
                float v0 = cc[m][0][j], v1 = cc[m][1][j], v2 = cc[m][2][j], v3 = cc[m][3][j];
                float mx = fmaxf(fmaxf(v0, v1), fmaxf(v2, v3));
                mx = fmaxf(mx, __shfl_xor(mx, 1));
                mx = fmaxf(mx, __shfl_xor(mx, 2));
                mx = fmaxf(mx, __shfl_xor(mx, 4));
                mx = fmaxf(mx, __shfl_xor(mx, 8));
                float e0 = __expf(v0 - mx), e1 = __expf(v1 - mx);
                float e2 = __expf(v2 - mx), e3 = __expf(v3 - mx);
                float sm = e0 + e1 + e2 + e3;
                sm += __shfl_xor(sm, 1); sm += __shfl_xor(sm, 2);
                sm += __shfl_xor(sm, 4); sm += __shfl_xor(sm, 8);
                float rs = 1.f / sm;
                int row = m*16 + lg*4 + j;
                PB[h][row*LDT +  0 + l15] = f2bf(e0 * rs);
                PB[h][row*LDT + 16 + l15] = f2bf(e1 * rs);
                PB[h][row*LDT + 32 + l15] = f2bf(e2 * rs);
                PB[h][row*LDT + 48 + l15] = f2bf(e3 * rs);
            }
        }
    }

    // ---- P5: pu_h = P_h @ hu_kv ; write into RA (pu_cat, cols h*32..) ----
    {
        const int h = wv;
        bf16x8 bv[2][2];
        #pragma unroll
        for (int nn = 0; nn < 2; ++nn)
            #pragma unroll
            for (int k = 0; k < 2; ++k)
                bv[nn][k] = ldbf8(&HUKVT[(nn*16 + l15)*LDT + k*32 + lg*8]);
        #pragma unroll
        for (int m = 0; m < 4; ++m) {
            bf16x8 a0 = ldbf8(&PB[h][(m*16 + l15)*LDT +  0 + lg*8]);
            bf16x8 a1 = ldbf8(&PB[h][(m*16 + l15)*LDT + 32 + lg*8]);
            #pragma unroll
            for (int nn = 0; nn < 2; ++nn) {
                f32x4 acc = {0.f, 0.f, 0.f, 0.f};
                acc = __builtin_amdgcn_mfma_f32_16x16x32_bf16(a0, bv[nn][0], acc, 0, 0, 0);
                acc = __builtin_amdgcn_mfma_f32_16x16x32_bf16(a1, bv[nn][1], acc, 0, 0, 0);
                #pragma unroll
                for (int j = 0; j < 4; ++j)
                    RA[(m*16 + lg*4 + j)*LDA + h*32 + nn*16 + l15] = f2bf(acc[j]);
            }
        }
    }
    __syncthreads();

    // ---- P6: upd = pu_cat @ O + cvec ; x1 = x + gamma*upd -> out (fp32) ----
    {
        const int n0 = wv * 32;
        const short* Ot = wsS + OT_OFF;
        bf16x8 bo[2][4];
        #pragma unroll
        for (int nn = 0; nn < 2; ++nn)
            #pragma unroll
            for (int k = 0; k < 4; ++k)
                bo[nn][k] = ldbf8(&Ot[(n0 + nn*16 + l15)*128 + k*32 + lg*8]);
        float cv[2], gm[2];
        #pragma unroll
        for (int nn = 0; nn < 2; ++nn) {
            int col = n0 + nn*16 + l15;
            cv[nn] = cvec[col];
            gm[nn] = gamma[col];
        }
        #pragma unroll
        for (int m = 0; m < 4; ++m) {
            bf16x8 a[4];
            #pragma unroll
            for (int k = 0; k < 4; ++k)
                a[k] = ldbf8(&RA[(m*16 + l15)*LDA + k*32 + lg*8]);
            #pragma unroll
            for (int nn = 0; nn < 2; ++nn) {
                f32x4 acc = {0.f, 0.f, 0.f, 0.f};
                #pragma unroll
                for (int k = 0; k < 4; ++k)
                    acc = __builtin_amdgcn_mfma_f32_16x16x32_bf16(a[k], bo[nn][k], acc, 0, 0, 0);
                int col = n0 + nn*16 + l15;
                #pragma unroll
                for (int j = 0; j < 4; ++j) {
                    int row = m*16 + lg*4 + j;
                    float xv = xw[row*128 + col];
                    outw[row*128 + col] = xv + gm[nn] * (acc[j] + cv[nn]);
                }
            }
        }
    }
    __syncthreads();

    // ---- P7: LN2 on x1 (from out) -> h2 (bf16) in RA ----
    {
        int s = tid >> 2, c = tid & 3;
        float4 xr[8];
        float sum = 0.f, sq = 0.f;
        #pragma unroll
        for (int j = 0; j < 8; ++j) {
            xr[j] = *(const float4*)&outw[s*128 + c*32 + j*4];
            sum += xr[j].x + xr[j].y + xr[j].z + xr[j].w;
            sq  += xr[j].x*xr[j].x + xr[j].y*xr[j].y + xr[j].z*xr[j].z + xr[j].w*xr[j].w;
        }
        sum += __shfl_xor(sum, 1); sq += __shfl_xor(sq, 1);
        sum += __shfl_xor(sum, 2); sq += __shfl_xor(sq, 2);
        float mean = sum * (1.f/128.f);
        float var  = sq * (1.f/128.f) - mean*mean;
        float rinv = rsqrtf(var + 1e-5f);
        #pragma unroll
        for (int j = 0; j < 8; ++j) {
            s16x4 hv;
            hv.x = f2bf((xr[j].x - mean) * rinv);
            hv.y = f2bf((xr[j].y - mean) * rinv);
            hv.z = f2bf((xr[j].z - mean) * rinv);
            hv.w = f2bf((xr[j].w - mean) * rinv);
            *(s16x4*)&RA[s*LDA + c*32 + j*4] = hv;
        }
    }
    __syncthreads();

    // ---- P8: t1 = gelu(h2 @ W1 + b1) (keep in regs, then overwrite RA) ----
    {
        const int n0 = wv * 32;
        const short* W1t = wsS + W1T_OFF;
        bf16x8 bw[2][4];
        #pragma unroll
        for (int nn = 0; nn < 2; ++nn)
            #pragma unroll
            for (int k = 0; k < 4; ++k)
                bw[nn][k] = ldbf8(&W1t[(n0 + nn*16 + l15)*128 + k*32 + lg*8]);
        float bb[2];
        #pragma unroll
        for (int nn = 0; nn < 2; ++nn) bb[nn] = b1[n0 + nn*16 + l15];
        short tval[4][2][4];
        #pragma unroll
        for (int m = 0; m < 4; ++m) {
            bf16x8 a[4];
            #pragma unroll
            for (int k = 0; k < 4; ++k)
                a[k] = ldbf8(&RA[(m*16 + l15)*LDA + k*32 + lg*8]);
            #pragma unroll
            for (int nn = 0; nn < 2; ++nn) {
                f32x4 acc = {0.f, 0.f, 0.f, 0.f};
                #pragma unroll
                for (int k = 0; k < 4; ++k)
                    acc = __builtin_amdgcn_mfma_f32_16x16x32_bf16(a[k], bw[nn][k], acc, 0, 0, 0);
                #pragma unroll
                for (int j = 0; j < 4; ++j) {
                    float t = acc[j] + bb[nn];
                    float u = 0.7978845608028654f * (t + 0.044715f*t*t*t);
                    u = fminf(fmaxf(u, -15.f), 15.f);
                    float e = __expf(2.f * u);
                    float g = 0.5f * t * (1.f + (e - 1.f) / (e + 1.f));
                    tval[m][nn][j] = f2bf(g);
                }
            }
        }
        __syncthreads();   // all h2 reads done
        #pragma unroll
        for (int m = 0; m < 4; ++m)
            #pragma unroll
            for (int nn = 0; nn < 2; ++nn)
                #pragma unroll
                for (int j = 0; j < 4; ++j)
                    RA[(m*16 + lg*4 + j)*LDA + n0 + nn*16 + l15] = tval[m][nn][j];
    }
    __syncthreads();

    // ---- P9: m = t1 @ W2 + b2 ; out = x1 + gmlp*m ----
    {
        const int n0 = wv * 32;
        const short* W2t = wsS + W2T_OFF;
        bf16x8 bw[2][4];
        #pragma unroll
        for (int nn = 0; nn < 2; ++nn)
            #pragma unroll
            for (int k = 0; k < 4; ++k)
                bw[nn][k] = ldbf8(&W2t[(n0 + nn*16 + l15)*128 + k*32 + lg*8]);
        float bb[2];
        #pragma unroll
        for (int nn = 0; nn < 2; ++nn) bb[nn] = b2[n0 + nn*16 + l15];
        const float gmv = gmlp_p[0];
        #pragma unroll
        for (int m = 0; m < 4; ++m) {
            bf16x8 a[4];
            #pragma unroll
            for (int k = 0; k < 4; ++k)
                a[k] = ldbf8(&RA[(m*16 + l15)*LDA + k*32 + lg*8]);
            #pragma unroll
            for (int nn = 0; nn < 2; ++nn) {
                f32x4 acc = {0.f, 0.f, 0.f, 0.f};
                #pragma unroll
                for (int k = 0; k < 4; ++k)
                    acc = __builtin_amdgcn_mfma_f32_16x16x32_bf16(a[k], bw[nn][k], acc, 0, 0, 0);
                int col = n0 + nn*16 + l15;
                #pragma unroll
                for (int j = 0; j < 4; ++j) {
                    int row = m*16 + lg*4 + j;
                    float x1v = outw[row*128 + col];
                    outw[row*128 + col] = x1v + gmv * (acc[j] + bb[nn]);
                }
            }
        }
    }
}

extern "C" void kernel_launch(void* const* d_in, const int* in_sizes, int n_in,
                              void* d_out, int out_size, void* d_ws, size_t ws_size,
                              hipStream_t stream) {
    const float* x     = (const float*)d_in[0];
    const float* Wq_u  = (const float*)d_in[1];
    const float* Wq_v  = (const float*)d_in[2];
    const float* Wkv_u = (const float*)d_in[3];
    const float* Wkv_v = (const float*)d_in[4];
    const float* kv_b  = (const float*)d_in[5];
    const float* Wo_u  = (const float*)d_in[6];
    const float* Wo_v  = (const float*)d_in[7];
    const float* gamma = (const float*)d_in[8];
    const float* W1    = (const float*)d_in[9];
    const float* b1    = (const float*)d_in[10];
    const float* W2    = (const float*)d_in[11];
    const float* b2    = (const float*)d_in[12];
    const float* gmlp  = (const float*)d_in[13];
    short* wsS  = (short*)d_ws;
    float* cvec = (float*)((char*)d_ws + CVEC_BYTE);
    float* out  = (float*)d_out;

    fam_pre<<<49, 256, 0, stream>>>(Wq_u, Wq_v, Wkv_u, Wkv_v, kv_b, Wo_u, Wo_v, W1, W2, wsS, cvec);
    fam_main<<<NWIN, 256, 0, stream>>>(x, wsS, cvec, gamma, b1, b2, gmlp, out);
}

// Round 3
// 98.252 us; speedup vs baseline: 29.5581x; 1.3143x over previous
//
#include <hip/hip_runtime.h>

// B=2,G=1024,S=64,L=16,F=8 -> LF=128, ATT=128, RANK=32, HC=32, NH=4. NWIN=2048.
#define NWIN 2048

// ws layout (shorts = bf16), then cvec (float) at byte 122880
#define WUT_OFF 0        // [64][128]  B^T for [hu_q|hu_kv] = [Wq_u|Wkv_u] transposed
#define MT_OFF  8192     // [4][32][32] MT[h][r][u] = M[h][u][r]/sqrt(32)
#define OT_OFF  12288    // [128][128]  OT[j][h*32+r]
#define W1T_OFF 28672    // [128][128]  W1T[i][k] = W1[k][i]
#define W2T_OFF 45056    // [128][128]  W2T[j][k] = W2[k][j]
#define CVEC_BYTE 122880

typedef __attribute__((ext_vector_type(8))) __bf16 bf16x8;
typedef __attribute__((ext_vector_type(8))) short s16x8;
typedef __attribute__((ext_vector_type(4))) short s16x4;
typedef __attribute__((ext_vector_type(4))) float f32x4;

static __device__ inline short f2bf(float f) {
    unsigned u = __builtin_bit_cast(unsigned, f);
    u += 0x7FFFu + ((u >> 16) & 1u);
    return (short)(u >> 16);
}
static __device__ inline float bf2f(short h) {
    unsigned u = ((unsigned)(unsigned short)h) << 16;
    return __builtin_bit_cast(float, u);
}
static __device__ inline bf16x8 ldbf8(const short* p) {
    return __builtin_bit_cast(bf16x8, *(const s16x8*)p);
}

// ---------------- precompute: build bf16 B^T tables in ws ----------------
__global__ __launch_bounds__(256) void fam_pre(
    const float* __restrict__ Wq_u, const float* __restrict__ Wq_v,
    const float* __restrict__ Wkv_u, const float* __restrict__ Wkv_v,
    const float* __restrict__ kv_b, const float* __restrict__ Wo_u,
    const float* __restrict__ Wo_v, const float* __restrict__ W1,
    const float* __restrict__ W2, short* __restrict__ wsS, float* __restrict__ cvec)
{
    const int b = blockIdx.x, tid = threadIdx.x;
    if (b < 16) {
        __shared__ float Wv[4096];   // Wkv_v v-part [r][c]  (32x128)
        __shared__ float Wu[4096];   // Wo_u [att][u]        (128x32)
        __shared__ float N[4096];    // N[h][u][r]
        for (int i = tid; i < 4096; i += 256) {
            int r = i >> 7, c = i & 127;
            Wv[i] = Wkv_v[r*256 + 128 + c];
            Wu[i] = Wo_u[i];
        }
        __syncthreads();
        for (int i = tid; i < 4096; i += 256) {
            int h = i >> 10, u = (i >> 5) & 31, r = i & 31;
            float acc = 0.f;
            for (int c = 0; c < 32; ++c) acc += Wv[r*128 + h*32 + c] * Wu[(h*32 + c)*32 + u];
            N[i] = acc;
        }
        __syncthreads();
        for (int i = tid; i < 1024; i += 256) {
            int jj = i >> 7, hr = i & 127;
            int j = b*8 + jj, h = hr >> 5, r = hr & 31;
            float acc = 0.f;
            for (int u = 0; u < 32; ++u) acc += N[h*1024 + u*32 + r] * Wo_v[u*128 + j];
            wsS[OT_OFF + j*128 + hr] = f2bf(acc);
        }
    } else if (b < 32) {
        int i0 = (b - 16) * 8;
        for (int t = tid; t < 1024; t += 256) {
            int ii = t >> 7, k = t & 127, i = i0 + ii;
            wsS[W1T_OFF + i*128 + k] = f2bf(W1[k*128 + i]);
        }
    } else if (b < 48) {
        int j0 = (b - 32) * 8;
        for (int t = tid; t < 1024; t += 256) {
            int jj = t >> 7, k = t & 127, j = j0 + jj;
            wsS[W2T_OFF + j*128 + k] = f2bf(W2[k*128 + j]);
        }
    } else {
        __shared__ float Aq[4096];   // Wq_v [u][128]
        __shared__ float Ak[4096];   // Wkv_v k-part [r][c]
        __shared__ float ov[32];
        for (int i = tid; i < 4096; i += 256) {
            int r = i >> 7, c = i & 127;
            Aq[i] = Wq_v[i];
            Ak[i] = Wkv_v[r*256 + c];
        }
        for (int i = tid; i < 8192; i += 256) {
            int n = i >> 7, k = i & 127;
            wsS[WUT_OFF + i] = f2bf(n < 32 ? Wq_u[k*32 + n] : Wkv_u[k*32 + (n - 32)]);
        }
        __syncthreads();
        const float sc = 0.17677669529663687f;  // 1/sqrt(32)
        for (int i = tid; i < 4096; i += 256) {
            int h = i >> 10, r = (i >> 5) & 31, u = i & 31;
            float acc = 0.f;
            for (int c = 0; c < 32; ++c) acc += Aq[u*128 + h*32 + c] * Ak[r*128 + h*32 + c];
            wsS[MT_OFF + h*1024 + r*32 + u] = f2bf(acc * sc);
        }
        if (tid < 32) {
            float a = 0.f;
            for (int att = 0; att < 128; ++att) a += kv_b[128 + att] * Wo_u[att*32 + tid];
            ov[tid] = a;
        }
        __syncthreads();
        if (tid < 128) {
            float a = 0.f;
            for (int u = 0; u < 32; ++u) a += ov[u] * Wo_v[u*128 + tid];
            cvec[tid] = a;
        }
    }
}

// ---------------- main fused kernel: 1 block = 1 window, 4 waves ----------------
#define LDA 136   // RA row stride (shorts): 272B rows, 2-way bank alias on b128 (free)
#define LDH 40    // HUQ/HUKV/HB row stride (shorts): 80B rows, 16B-aligned, 2-way
#define LDP 80    // fp8 row stride in BYTES (aliases HB rows / KVT8 rows)

__global__ __launch_bounds__(256, 3) void fam_main(
    const float* __restrict__ x, const short* __restrict__ wsS,
    const float* __restrict__ cvec, const float* __restrict__ gamma,
    const float* __restrict__ b1, const float* __restrict__ b2,
    const float* __restrict__ gmlp_p, float* __restrict__ out)
{
    __shared__ short RA[64 * LDA];          // h -> pu_cat -> x1(bf16)/h2 -> t1   17408B
    __shared__ short HUQ[64 * LDH];         // hu_q [s][r]                         5120B
    __shared__ short HUKV[64 * LDH];        // hu_kv [t][r] (bf16, A of S^T)       5120B
    __shared__ unsigned char KVT8[32 * LDP];// hu_kv^T [u][t] fp8 (B of PV)        2560B
    __shared__ short HB[4][64 * LDH];       // per head: qt bf16 [s][r]; then P fp8 [s][80B] aliased  20480B

    const int tid = threadIdx.x;
    const int l   = tid & 63;
    const int wv  = tid >> 6;
    const int l15 = l & 15;
    const int lg  = l >> 4;
    const size_t base = (size_t)blockIdx.x * 8192;
    const float* __restrict__ xw   = x + base;
    float* __restrict__       outw = out + base;

    // ---- P1: LN1 -> h (bf16) in RA ----
    {
        int s = tid >> 2, c = tid & 3;
        float4 xr[8];
        float sum = 0.f, sq = 0.f;
        #pragma unroll
        for (int j = 0; j < 8; ++j) {
            xr[j] = *(const float4*)&xw[s*128 + c*32 + j*4];
            sum += xr[j].x + xr[j].y + xr[j].z + xr[j].w;
            sq  += xr[j].x*xr[j].x + xr[j].y*xr[j].y + xr[j].z*xr[j].z + xr[j].w*xr[j].w;
        }
        sum += __shfl_xor(sum, 1); sq += __shfl_xor(sq, 1);
        sum += __shfl_xor(sum, 2); sq += __shfl_xor(sq, 2);
        float mean = sum * (1.f/128.f);
        float var  = sq * (1.f/128.f) - mean*mean;
        float rinv = rsqrtf(var + 1e-5f);
        #pragma unroll
        for (int j = 0; j < 8; ++j) {
            s16x4 hv;
            hv.x = f2bf((xr[j].x - mean) * rinv);
            hv.y = f2bf((xr[j].y - mean) * rinv);
            hv.z = f2bf((xr[j].z - mean) * rinv);
            hv.w = f2bf((xr[j].w - mean) * rinv);
            *(s16x4*)&RA[s*LDA + c*32 + j*4] = hv;
        }
    }
    __syncthreads();   // B1

    // ---- P2: [hu_q(32) | hu_kv(32)] = h @ [Wq_u|Wkv_u]; wave = 16-col strip ----
    {
        const short* Bt = wsS + WUT_OFF;
        bf16x8 bfr[4];
        #pragma unroll
        for (int k = 0; k < 4; ++k)
            bfr[k] = ldbf8(&Bt[(wv*16 + l15)*128 + k*32 + lg*8]);
        #pragma unroll
        for (int m = 0; m < 4; ++m) {
            f32x4 acc = {0.f, 0.f, 0.f, 0.f};
            #pragma unroll
            for (int k = 0; k < 4; ++k) {
                bf16x8 a = ldbf8(&RA[(m*16 + l15)*LDA + k*32 + lg*8]);
                acc = __builtin_amdgcn_mfma_f32_16x16x32_bf16(a, bfr[k], acc, 0, 0, 0);
            }
            if (wv < 2) {
                int col = wv*16 + l15;
                #pragma unroll
                for (int j = 0; j < 4; ++j)
                    HUQ[(m*16 + lg*4 + j)*LDH + col] = f2bf(acc[j]);
            } else {
                int u = (wv - 2)*16 + l15;
                #pragma unroll
                for (int j = 0; j < 4; ++j)
                    HUKV[(m*16 + lg*4 + j)*LDH + u] = f2bf(acc[j]);
                unsigned w = 0;
                w = __builtin_amdgcn_cvt_pk_fp8_f32(acc[0], acc[1], w, false);
                w = __builtin_amdgcn_cvt_pk_fp8_f32(acc[2], acc[3], w, true);
                *(unsigned*)&KVT8[u*LDP + m*16 + lg*4] = w;
            }
        }
    }
    __syncthreads();   // B2

    // ---- P3/P4/P5: per-head attention, fully wave-local (h = wv) ----
    {
        const int h = wv;
        short* qtb = &HB[h][0];
        // qt = hu_q @ M_h   (K=32), write [s][r] to HB[h]
        bf16x8 bm0 = ldbf8(&wsS[MT_OFF + h*1024 + l15*32 + lg*8]);
        bf16x8 bm1 = ldbf8(&wsS[MT_OFF + h*1024 + (16 + l15)*32 + lg*8]);
        #pragma unroll
        for (int m = 0; m < 4; ++m) {
            bf16x8 aq = ldbf8(&HUQ[(m*16 + l15)*LDH + lg*8]);
            f32x4 z = {0.f, 0.f, 0.f, 0.f};
            f32x4 a0 = __builtin_amdgcn_mfma_f32_16x16x32_bf16(aq, bm0, z, 0, 0, 0);
            f32x4 a1 = __builtin_amdgcn_mfma_f32_16x16x32_bf16(aq, bm1, z, 0, 0, 0);
            #pragma unroll
            for (int j = 0; j < 4; ++j) {
                int row = (m*16 + lg*4 + j)*LDH;
                qtb[row + l15]      = f2bf(a0[j]);
                qtb[row + 16 + l15] = f2bf(a1[j]);
            }
        }
        // S^T[t][s] = sum_r kv[t][r] * qt[s][r]  (swapped operands)
        bf16x8 av[4], bq[4];
        #pragma unroll
        for (int m = 0; m < 4; ++m) av[m] = ldbf8(&HUKV[(m*16 + l15)*LDH + lg*8]);
        #pragma unroll
        for (int n = 0; n < 4; ++n) bq[n] = ldbf8(&qtb[(n*16 + l15)*LDH + lg*8]);
        f32x4 cc[4][4];
        #pragma unroll
        for (int m = 0; m < 4; ++m)
            #pragma unroll
            for (int n = 0; n < 4; ++n) {
                f32x4 z = {0.f, 0.f, 0.f, 0.f};
                cc[m][n] = __builtin_amdgcn_mfma_f32_16x16x32_bf16(av[m], bq[n], z, 0, 0, 0);
            }
        // softmax over t for each s = n*16+l15 (16 in-lane values + 2 shfl), P -> fp8
        unsigned char* P8 = (unsigned char*)qtb;
        #pragma unroll
        for (int n = 0; n < 4; ++n) {
            float mx = -1e30f;
            #pragma unroll
            for (int m = 0; m < 4; ++m)
                #pragma unroll
                for (int j = 0; j < 4; ++j) mx = fmaxf(mx, cc[m][n][j]);
            mx = fmaxf(mx, __shfl_xor(mx, 16));
            mx = fmaxf(mx, __shfl_xor(mx, 32));
            float e[4][4];
            float sm = 0.f;
            #pragma unroll
            for (int m = 0; m < 4; ++m)
                #pragma unroll
                for (int j = 0; j < 4; ++j) { e[m][j] = __expf(cc[m][n][j] - mx); sm += e[m][j]; }
            sm += __shfl_xor(sm, 16);
            sm += __shfl_xor(sm, 32);
            float rs = 1.f / sm;
            int srow = (n*16 + l15) * LDP;
            #pragma unroll
            for (int m = 0; m < 4; ++m) {
                unsigned w = 0;
                w = __builtin_amdgcn_cvt_pk_fp8_f32(e[m][0]*rs, e[m][1]*rs, w, false);
                w = __builtin_amdgcn_cvt_pk_fp8_f32(e[m][2]*rs, e[m][3]*rs, w, true);
                *(unsigned*)&P8[srow + m*16 + lg*4] = w;
            }
        }
        // PV (fp8): pu[s][u] = sum_t P[s][t] kv[t][u]; write pu_cat into RA cols h*32..
        long a8[4][2], b8[2][2];
        #pragma unroll
        for (int m = 0; m < 4; ++m)
            #pragma unroll
            for (int kb = 0; kb < 2; ++kb)
                __builtin_memcpy(&a8[m][kb], &P8[(m*16 + l15)*LDP + kb*32 + lg*8], 8);
        #pragma unroll
        for (int nn = 0; nn < 2; ++nn)
            #pragma unroll
            for (int kb = 0; kb < 2; ++kb)
                __builtin_memcpy(&b8[nn][kb], &KVT8[(nn*16 + l15)*LDP + kb*32 + lg*8], 8);
        #pragma unroll
        for (int m = 0; m < 4; ++m)
            #pragma unroll
            for (int nn = 0; nn < 2; ++nn) {
                f32x4 acc = {0.f, 0.f, 0.f, 0.f};
                acc = __builtin_amdgcn_mfma_f32_16x16x32_fp8_fp8(a8[m][0], b8[nn][0], acc, 0, 0, 0);
                acc = __builtin_amdgcn_mfma_f32_16x16x32_fp8_fp8(a8[m][1], b8[nn][1], acc, 0, 0, 0);
                #pragma unroll
                for (int j = 0; j < 4; ++j)
                    RA[(m*16 + lg*4 + j)*LDA + h*32 + nn*16 + l15] = f2bf(acc[j]);
            }
    }
    __syncthreads();   // B3: pu_cat complete

    const int n0 = wv * 32;
    float x1v[4][2][4];

    // ---- P6: upd = pu_cat @ O + cvec ; x1 = x + gamma*upd (REGISTERS) ----
    {
        float xr[4][2][4];
        #pragma unroll
        for (int m = 0; m < 4; ++m)
            #pragma unroll
            for (int nn = 0; nn < 2; ++nn)
                #pragma unroll
                for (int j = 0; j < 4; ++j)
                    xr[m][nn][j] = xw[(m*16 + lg*4 + j)*128 + n0 + nn*16 + l15];
        const short* Ot = wsS + OT_OFF;
        bf16x8 bo[2][4];
        #pragma unroll
        for (int nn = 0; nn < 2; ++nn)
            #pragma unroll
            for (int k = 0; k < 4; ++k)
                bo[nn][k] = ldbf8(&Ot[(n0 + nn*16 + l15)*128 + k*32 + lg*8]);
        float cv[2], gm[2];
        #pragma unroll
        for (int nn = 0; nn < 2; ++nn) {
            cv[nn] = cvec[n0 + nn*16 + l15];
            gm[nn] = gamma[n0 + nn*16 + l15];
        }
        f32x4 acc[4][2];
        #pragma unroll
        for (int m = 0; m < 4; ++m)
            #pragma unroll
            for (int nn = 0; nn < 2; ++nn) acc[m][nn] = (f32x4){0.f,0.f,0.f,0.f};
        #pragma unroll
        for (int m = 0; m < 4; ++m) {
            #pragma unroll
            for (int k = 0; k < 4; ++k) {
                bf16x8 a = ldbf8(&RA[(m*16 + l15)*LDA + k*32 + lg*8]);
                #pragma unroll
                for (int nn = 0; nn < 2; ++nn)
                    acc[m][nn] = __builtin_amdgcn_mfma_f32_16x16x32_bf16(a, bo[nn][k], acc[m][nn], 0, 0, 0);
            }
        }
        __syncthreads();   // B4: all pu_cat reads done, RA reusable
        #pragma unroll
        for (int m = 0; m < 4; ++m)
            #pragma unroll
            for (int nn = 0; nn < 2; ++nn)
                #pragma unroll
                for (int j = 0; j < 4; ++j) {
                    float v = xr[m][nn][j] + gm[nn] * (acc[m][nn][j] + cv[nn]);
                    x1v[m][nn][j] = v;
                    RA[(m*16 + lg*4 + j)*LDA + n0 + nn*16 + l15] = f2bf(v);
                }
    }
    __syncthreads();   // B5: x1 (bf16) in RA complete

    // ---- P7: LN2 stats + normalize RA in place (LDS only) ----
    {
        int s = tid >> 2, c = tid & 3;
        float sum = 0.f, sq = 0.f;
        #pragma unroll
        for (int jj = 0; jj < 8; ++jj) {
            s16x4 hv = *(const s16x4*)&RA[s*LDA + c*32 + jj*4];
            #pragma unroll
            for (int e = 0; e < 4; ++e) {
                float f = bf2f(hv[e]);
                sum += f; sq += f*f;
            }
        }
        sum += __shfl_xor(sum, 1); sq += __shfl_xor(sq, 1);
        sum += __shfl_xor(sum, 2); sq += __shfl_xor(sq, 2);
        float mean = sum * (1.f/128.f);
        float var  = sq * (1.f/128.f) - mean*mean;
        float rinv = rsqrtf(var + 1e-5f);
        #pragma unroll
        for (int jj = 0; jj < 8; ++jj) {
            s16x4 hv = *(const s16x4*)&RA[s*LDA + c*32 + jj*4];
            s16x4 ov;
            #pragma unroll
            for (int e = 0; e < 4; ++e) ov[e] = f2bf((bf2f(hv[e]) - mean) * rinv);
            *(s16x4*)&RA[s*LDA + c*32 + jj*4] = ov;
        }
    }
    __syncthreads();   // B6: h2 in RA

    // ---- P8: t1 = gelu(h2 @ W1 + b1) ----
    {
        const short* W1t = wsS + W1T_OFF;
        bf16x8 bw[2][4];
        #pragma unroll
        for (int nn = 0; nn < 2; ++nn)
            #pragma unroll
            for (int k = 0; k < 4; ++k)
                bw[nn][k] = ldbf8(&W1t[(n0 + nn*16 + l15)*128 + k*32 + lg*8]);
        float bb[2];
        #pragma unroll
        for (int nn = 0; nn < 2; ++nn) bb[nn] = b1[n0 + nn*16 + l15];
        short tval[4][2][4];
        #pragma unroll
        for (int m = 0; m < 4; ++m) {
            bf16x8 a[4];
            #pragma unroll
            for (int k = 0; k < 4; ++k)
                a[k] = ldbf8(&RA[(m*16 + l15)*LDA + k*32 + lg*8]);
            #pragma unroll
            for (int nn = 0; nn < 2; ++nn) {
                f32x4 acc = {0.f, 0.f, 0.f, 0.f};
                #pragma unroll
                for (int k = 0; k < 4; ++k)
                    acc = __builtin_amdgcn_mfma_f32_16x16x32_bf16(a[k], bw[nn][k], acc, 0, 0, 0);
                #pragma unroll
                for (int j = 0; j < 4; ++j) {
                    float t = acc[j] + bb[nn];
                    float u = 0.7978845608028654f * (t + 0.044715f*t*t*t);
                    u = fminf(fmaxf(u, -15.f), 15.f);
                    float e = __expf(2.f * u);
                    float g = 0.5f * t * (1.f + (e - 1.f) / (e + 1.f));
                    tval[m][nn][j] = f2bf(g);
                }
            }
        }
        __syncthreads();   // B7: all h2 reads done
        #pragma unroll
        for (int m = 0; m < 4; ++m)
            #pragma unroll
            for (int nn = 0; nn < 2; ++nn)
                #pragma unroll
                for (int j = 0; j < 4; ++j)
                    RA[(m*16 + lg*4 + j)*LDA + n0 + nn*16 + l15] = tval[m][nn][j];
    }
    __syncthreads();   // B8: t1 in RA

    // ---- P9: m = t1 @ W2 + b2 ; out = x1(reg) + gmlp*m (single global write) ----
    {
        const short* W2t = wsS + W2T_OFF;
        bf16x8 bw[2][4];
        #pragma unroll
        for (int nn = 0; nn < 2; ++nn)
            #pragma unroll
            for (int k = 0; k < 4; ++k)
                bw[nn][k] = ldbf8(&W2t[(n0 + nn*16 + l15)*128 + k*32 + lg*8]);
        float bb[2];
        #pragma unroll
        for (int nn = 0; nn < 2; ++nn) bb[nn] = b2[n0 + nn*16 + l15];
        const float gmv = gmlp_p[0];
        #pragma unroll
        for (int m = 0; m < 4; ++m) {
            bf16x8 a[4];
            #pragma unroll
            for (int k = 0; k < 4; ++k)
                a[k] = ldbf8(&RA[(m*16 + l15)*LDA + k*32 + lg*8]);
            #pragma unroll
            for (int nn = 0; nn < 2; ++nn) {
                f32x4 acc = {0.f, 0.f, 0.f, 0.f};
                #pragma unroll
                for (int k = 0; k < 4; ++k)
                    acc = __builtin_amdgcn_mfma_f32_16x16x32_bf16(a[k], bw[nn][k], acc, 0, 0, 0);
                #pragma unroll
                for (int j = 0; j < 4; ++j)
                    outw[(m*16 + lg*4 + j)*128 + n0 + nn*16 + l15] =
                        x1v[m][nn][j] + gmv * (acc[j] + bb[nn]);
            }
        }
    }
}

extern "C" void kernel_launch(void* const* d_in, const int* in_sizes, int n_in,
                              void* d_out, int out_size, void* d_ws, size_t ws_size,
                              hipStream_t stream) {
    const float* x     = (const float*)d_in[0];
    const float* Wq_u  = (const float*)d_in[1];
    const float* Wq_v  = (const float*)d_in[2];
    const float* Wkv_u = (const float*)d_in[3];
    const float* Wkv_v = (const float*)d_in[4];
    const float* kv_b  = (const float*)d_in[5];
    const float* Wo_u  = (const float*)d_in[6];
    const float* Wo_v  = (const float*)d_in[7];
    const float* gamma = (const float*)d_in[8];
    const float* W1    = (const float*)d_in[9];
    const float* b1    = (const float*)d_in[10];
    const float* W2    = (const float*)d_in[11];
    const float* b2    = (const float*)d_in[12];
    const float* gmlp  = (const float*)d_in[13];
    short* wsS  = (short*)d_ws;
    float* cvec = (float*)((char*)d_ws + CVEC_BYTE);
    float* out  = (float*)d_out;

    fam_pre<<<49, 256, 0, stream>>>(Wq_u, Wq_v, Wkv_u, Wkv_v, kv_b, Wo_u, Wo_v, W1, W2, wsS, cvec);
    fam_main<<<NWIN, 256, 0, stream>>>(x, wsS, cvec, gamma, b1, b2, gmlp, out);
}

// Round 6
// 97.226 us; speedup vs baseline: 29.8702x; 1.0106x over previous
//
#include <hip/hip_runtime.h>

// B=2,G=1024,S=64,L=16,F=8 -> LF=128, ATT=128, RANK=32, HC=32, NH=4. NWIN=2048.
#define NWIN 2048

// ws layout (shorts = bf16), then cvec (float) at byte 122880. Total 123392 B (proven).
#define WUT_OFF 0        // [64][128]  B^T for [hu_q|hu_kv] = [Wq_u|Wkv_u] transposed
#define MT_OFF  8192     // [4][32][32] MT[h][r][u] = M[h][u][r]/sqrt(32)
#define OT_OFF  12288    // [128][128]  OT[j][h*32+r]
#define W1T_OFF 28672    // [128][128]  W1T[i][k] = W1[k][i]
#define W2T_OFF 45056    // [128][128]  W2T[j][k] = W2[k][j]
#define CVEC_BYTE 122880

typedef __attribute__((ext_vector_type(8))) __bf16 bf16x8;
typedef __attribute__((ext_vector_type(8))) short s16x8;
typedef __attribute__((ext_vector_type(4))) short s16x4;
typedef __attribute__((ext_vector_type(4))) float f32x4;

static __device__ inline short f2bf(float f) {
    unsigned u = __builtin_bit_cast(unsigned, f);
    u += 0x7FFFu + ((u >> 16) & 1u);
    return (short)(u >> 16);
}
static __device__ inline float bf2f(short h) {
    unsigned u = ((unsigned)(unsigned short)h) << 16;
    return __builtin_bit_cast(float, u);
}
static __device__ inline bf16x8 ldbf8(const short* p) {
    return __builtin_bit_cast(bf16x8, *(const s16x8*)p);
}

// ---------------- precompute (identical to round 3, proven) ----------------
__global__ __launch_bounds__(256) void fam_pre(
    const float* __restrict__ Wq_u, const float* __restrict__ Wq_v,
    const float* __restrict__ Wkv_u, const float* __restrict__ Wkv_v,
    const float* __restrict__ kv_b, const float* __restrict__ Wo_u,
    const float* __restrict__ Wo_v, const float* __restrict__ W1,
    const float* __restrict__ W2, short* __restrict__ wsS, float* __restrict__ cvec)
{
    const int b = blockIdx.x, tid = threadIdx.x;
    if (b < 16) {
        __shared__ float Wv[4096];   // Wkv_v v-part [r][c]  (32x128)
        __shared__ float Wu[4096];   // Wo_u [att][u]        (128x32)
        __shared__ float N[4096];    // N[h][u][r]
        for (int i = tid; i < 4096; i += 256) {
            int r = i >> 7, c = i & 127;
            Wv[i] = Wkv_v[r*256 + 128 + c];
            Wu[i] = Wo_u[i];
        }
        __syncthreads();
        for (int i = tid; i < 4096; i += 256) {
            int h = i >> 10, u = (i >> 5) & 31, r = i & 31;
            float acc = 0.f;
            for (int c = 0; c < 32; ++c) acc += Wv[r*128 + h*32 + c] * Wu[(h*32 + c)*32 + u];
            N[i] = acc;
        }
        __syncthreads();
        for (int i = tid; i < 1024; i += 256) {
            int jj = i >> 7, hr = i & 127;
            int j = b*8 + jj, h = hr >> 5, r = hr & 31;
            float acc = 0.f;
            for (int u = 0; u < 32; ++u) acc += N[h*1024 + u*32 + r] * Wo_v[u*128 + j];
            wsS[OT_OFF + j*128 + hr] = f2bf(acc);
        }
    } else if (b < 32) {
        int i0 = (b - 16) * 8;
        for (int t = tid; t < 1024; t += 256) {
            int ii = t >> 7, k = t & 127, i = i0 + ii;
            wsS[W1T_OFF + i*128 + k] = f2bf(W1[k*128 + i]);
        }
    } else if (b < 48) {
        int j0 = (b - 32) * 8;
        for (int t = tid; t < 1024; t += 256) {
            int jj = t >> 7, k = t & 127, j = j0 + jj;
            wsS[W2T_OFF + j*128 + k] = f2bf(W2[k*128 + j]);
        }
    } else {
        __shared__ float Aq[4096];   // Wq_v [u][128]
        __shared__ float Ak[4096];   // Wkv_v k-part [r][c]
        __shared__ float ov[32];
        for (int i = tid; i < 4096; i += 256) {
            int r = i >> 7, c = i & 127;
            Aq[i] = Wq_v[i];
            Ak[i] = Wkv_v[r*256 + c];
        }
        for (int i = tid; i < 8192; i += 256) {
            int n = i >> 7, k = i & 127;
            wsS[WUT_OFF + i] = f2bf(n < 32 ? Wq_u[k*32 + n] : Wkv_u[k*32 + (n - 32)]);
        }
        __syncthreads();
        const float sc = 0.17677669529663687f;  // 1/sqrt(32)
        for (int i = tid; i < 4096; i += 256) {
            int h = i >> 10, r = (i >> 5) & 31, u = i & 31;
            float acc = 0.f;
            for (int c = 0; c < 32; ++c) acc += Aq[u*128 + h*32 + c] * Ak[r*128 + h*32 + c];
            wsS[MT_OFF + h*1024 + r*32 + u] = f2bf(acc * sc);
        }
        if (tid < 32) {
            float a = 0.f;
            for (int att = 0; att < 128; ++att) a += kv_b[128 + att] * Wo_u[att*32 + tid];
            ov[tid] = a;
        }
        __syncthreads();
        if (tid < 128) {
            float a = 0.f;
            for (int u = 0; u < 32; ++u) a += ov[u] * Wo_v[u*128 + tid];
            cvec[tid] = a;
        }
    }
}

// ---------------- main fused kernel: 1 block = 1 window, 4 waves ----------------
// Kernel C (round-3, proven) + two structural deltas:
//   (1) x1/h2 live in XB (aliases dead HB region) instead of RA -> P6 interior barrier gone
//   (2) P8 writes t1 directly to RA (dead since P6) -> B7 + reg staging gone
// 6 barriers total. No new arithmetic paths, no inline asm, no layout changes.
#define LDA 136   // RA/XB row stride (shorts): 272B rows, 2-way bank alias (free)
#define LDH 40    // HUQ/HUKV/HB row stride (shorts): 80B rows, 16B-aligned
#define LDP 80    // fp8 row stride in BYTES (P in HB rows / KVT8 rows)

__global__ __launch_bounds__(256, 3) void fam_main(
    const float* __restrict__ x, const short* __restrict__ wsS,
    const float* __restrict__ cvec, const float* __restrict__ gamma,
    const float* __restrict__ b1, const float* __restrict__ b2,
    const float* __restrict__ gmlp_p, float* __restrict__ out)
{
    __shared__ __align__(16) short RA[64 * LDA];          // h -> pu_cat -> t1      17408B
    __shared__ __align__(16) short HUQ[64 * LDH];         // hu_q bf16 [s][r]        5120B
    __shared__ __align__(16) short HUKV[64 * LDH];        // hu_kv bf16 [t][r]       5120B
    __shared__ __align__(16) unsigned char KVT8[32 * LDP];// v fp8 [u][t]            2560B
    __shared__ __align__(16) short HB[4][64 * LDH];       // qt bf16 / P fp8 per head; later XB = x1/h2  20480B

    const int tid = threadIdx.x;
    const int l   = tid & 63;
    const int wv  = tid >> 6;
    const int l15 = l & 15;
    const int lg  = l >> 4;
    const size_t base = (size_t)blockIdx.x * 8192;
    const float* __restrict__ xw   = x + base;
    float* __restrict__       outw = out + base;

    // ---- P1: LN1 -> h (bf16) in RA ----
    {
        int s = tid >> 2, c = tid & 3;
        float4 xr[8];
        float sum = 0.f, sq = 0.f;
        #pragma unroll
        for (int j = 0; j < 8; ++j) {
            xr[j] = *(const float4*)&xw[s*128 + c*32 + j*4];
            sum += xr[j].x + xr[j].y + xr[j].z + xr[j].w;
            sq  += xr[j].x*xr[j].x + xr[j].y*xr[j].y + xr[j].z*xr[j].z + xr[j].w*xr[j].w;
        }
        sum += __shfl_xor(sum, 1); sq += __shfl_xor(sq, 1);
        sum += __shfl_xor(sum, 2); sq += __shfl_xor(sq, 2);
        float mean = sum * (1.f/128.f);
        float var  = sq * (1.f/128.f) - mean*mean;
        float rinv = rsqrtf(var + 1e-5f);
        #pragma unroll
        for (int j = 0; j < 8; ++j) {
            s16x4 hv;
            hv.x = f2bf((xr[j].x - mean) * rinv);
            hv.y = f2bf((xr[j].y - mean) * rinv);
            hv.z = f2bf((xr[j].z - mean) * rinv);
            hv.w = f2bf((xr[j].w - mean) * rinv);
            *(s16x4*)&RA[s*LDA + c*32 + j*4] = hv;
        }
    }
    __syncthreads();   // B1

    // ---- P2: [hu_q(32) | hu_kv(32)] = h @ [Wq_u|Wkv_u]; wave = 16-col strip ----
    {
        const short* Bt = wsS + WUT_OFF;
        bf16x8 bfr[4];
        #pragma unroll
        for (int k = 0; k < 4; ++k)
            bfr[k] = ldbf8(&Bt[(wv*16 + l15)*128 + k*32 + lg*8]);
        #pragma unroll
        for (int m = 0; m < 4; ++m) {
            f32x4 acc = {0.f, 0.f, 0.f, 0.f};
            #pragma unroll
            for (int k = 0; k < 4; ++k) {
                bf16x8 a = ldbf8(&RA[(m*16 + l15)*LDA + k*32 + lg*8]);
                acc = __builtin_amdgcn_mfma_f32_16x16x32_bf16(a, bfr[k], acc, 0, 0, 0);
            }
            if (wv < 2) {
                int col = wv*16 + l15;
                #pragma unroll
                for (int j = 0; j < 4; ++j)
                    HUQ[(m*16 + lg*4 + j)*LDH + col] = f2bf(acc[j]);
            } else {
                int u = (wv - 2)*16 + l15;
                #pragma unroll
                for (int j = 0; j < 4; ++j)
                    HUKV[(m*16 + lg*4 + j)*LDH + u] = f2bf(acc[j]);
                unsigned w = 0;
                w = __builtin_amdgcn_cvt_pk_fp8_f32(acc[0], acc[1], w, false);
                w = __builtin_amdgcn_cvt_pk_fp8_f32(acc[2], acc[3], w, true);
                *(unsigned*)&KVT8[u*LDP + m*16 + lg*4] = w;
            }
        }
    }
    __syncthreads();   // B2

    // ---- P3/P4/P5: per-head attention, wave-local (h = wv) ----
    {
        const int h = wv;
        short* qtb = &HB[h][0];
        // P3: qt = hu_q @ M_h (bf16), write [s][r] to HB[h]
        const short* Mt = wsS + MT_OFF + h*1024;
        bf16x8 bm0 = ldbf8(&Mt[l15*32 + lg*8]);
        bf16x8 bm1 = ldbf8(&Mt[(16 + l15)*32 + lg*8]);
        #pragma unroll
        for (int m = 0; m < 4; ++m) {
            bf16x8 aq = ldbf8(&HUQ[(m*16 + l15)*LDH + lg*8]);
            f32x4 z = {0.f, 0.f, 0.f, 0.f};
            f32x4 a0 = __builtin_amdgcn_mfma_f32_16x16x32_bf16(aq, bm0, z, 0, 0, 0);
            f32x4 a1 = __builtin_amdgcn_mfma_f32_16x16x32_bf16(aq, bm1, z, 0, 0, 0);
            #pragma unroll
            for (int j = 0; j < 4; ++j) {
                int row = (m*16 + lg*4 + j)*LDH;
                qtb[row + l15]      = f2bf(a0[j]);
                qtb[row + 16 + l15] = f2bf(a1[j]);
            }
        }
        // P4: S^T[t][s] = sum_r kv[t][r] * qt[s][r] (swapped operands, bf16)
        bf16x8 av[4], bq[4];
        #pragma unroll
        for (int m = 0; m < 4; ++m) av[m] = ldbf8(&HUKV[(m*16 + l15)*LDH + lg*8]);
        #pragma unroll
        for (int n = 0; n < 4; ++n) bq[n] = ldbf8(&qtb[(n*16 + l15)*LDH + lg*8]);
        f32x4 cc[4][4];
        #pragma unroll
        for (int m = 0; m < 4; ++m)
            #pragma unroll
            for (int n = 0; n < 4; ++n) {
                f32x4 z = {0.f, 0.f, 0.f, 0.f};
                cc[m][n] = __builtin_amdgcn_mfma_f32_16x16x32_bf16(av[m], bq[n], z, 0, 0, 0);
            }
        // softmax over t for each s = n*16+l15 (16 in-lane + 2 shfl), P -> fp8 in HB[h]
        unsigned char* P8 = (unsigned char*)qtb;
        #pragma unroll
        for (int n = 0; n < 4; ++n) {
            float mx = -1e30f;
            #pragma unroll
            for (int m = 0; m < 4; ++m)
                #pragma unroll
                for (int j = 0; j < 4; ++j) mx = fmaxf(mx, cc[m][n][j]);
            mx = fmaxf(mx, __shfl_xor(mx, 16));
            mx = fmaxf(mx, __shfl_xor(mx, 32));
            float e[4][4];
            float sm = 0.f;
            #pragma unroll
            for (int m = 0; m < 4; ++m)
                #pragma unroll
                for (int j = 0; j < 4; ++j) { e[m][j] = __expf(cc[m][n][j] - mx); sm += e[m][j]; }
            sm += __shfl_xor(sm, 16);
            sm += __shfl_xor(sm, 32);
            float rs = 1.f / sm;
            int srow = (n*16 + l15) * LDP;
            #pragma unroll
            for (int m = 0; m < 4; ++m) {
                unsigned w = 0;
                w = __builtin_amdgcn_cvt_pk_fp8_f32(e[m][0]*rs, e[m][1]*rs, w, false);
                w = __builtin_amdgcn_cvt_pk_fp8_f32(e[m][2]*rs, e[m][3]*rs, w, true);
                *(unsigned*)&P8[srow + m*16 + lg*4] = w;
            }
        }
        // P5: PV (fp8): pu[s][u] = sum_t P[s][t] v[t][u] -> pu_cat bf16 in RA
        long a8[4][2], b8[2][2];
        #pragma unroll
        for (int m = 0; m < 4; ++m)
            #pragma unroll
            for (int kb = 0; kb < 2; ++kb)
                __builtin_memcpy(&a8[m][kb], &P8[(m*16 + l15)*LDP + kb*32 + lg*8], 8);
        #pragma unroll
        for (int nn = 0; nn < 2; ++nn)
            #pragma unroll
            for (int kb = 0; kb < 2; ++kb)
                __builtin_memcpy(&b8[nn][kb], &KVT8[(nn*16 + l15)*LDP + kb*32 + lg*8], 8);
        #pragma unroll
        for (int m = 0; m < 4; ++m)
            #pragma unroll
            for (int nn = 0; nn < 2; ++nn) {
                f32x4 acc = {0.f,0.f,0.f,0.f};
                acc = __builtin_amdgcn_mfma_f32_16x16x32_fp8_fp8(a8[m][0], b8[nn][0], acc, 0, 0, 0);
                acc = __builtin_amdgcn_mfma_f32_16x16x32_fp8_fp8(a8[m][1], b8[nn][1], acc, 0, 0, 0);
                #pragma unroll
                for (int j = 0; j < 4; ++j)
                    RA[(m*16 + lg*4 + j)*LDA + h*32 + nn*16 + l15] = f2bf(acc[j]);
            }
    }
    __syncthreads();   // B3: pu_cat in RA complete; HB dead -> XB

    const int n0 = wv * 32;
    float x1v[4][2][4];
    short* XB = (short*)&HB[0][0];   // x1/h2 bf16 [64][LDA], 17408B <= 20480B

    // ---- P6: upd = pu_cat @ O + cvec ; x1 = x + gamma*upd (regs + XB bf16) ----
    {
        float xr[4][2][4];
        #pragma unroll
        for (int m = 0; m < 4; ++m)
            #pragma unroll
            for (int nn = 0; nn < 2; ++nn)
                #pragma unroll
                for (int j = 0; j < 4; ++j)
                    xr[m][nn][j] = xw[(m*16 + lg*4 + j)*128 + n0 + nn*16 + l15];
        const short* Ot = wsS + OT_OFF;
        bf16x8 bo[2][4];
        #pragma unroll
        for (int nn = 0; nn < 2; ++nn)
            #pragma unroll
            for (int k = 0; k < 4; ++k)
                bo[nn][k] = ldbf8(&Ot[(n0 + nn*16 + l15)*128 + k*32 + lg*8]);
        float cv[2], gm[2];
        #pragma unroll
        for (int nn = 0; nn < 2; ++nn) {
            cv[nn] = cvec[n0 + nn*16 + l15];
            gm[nn] = gamma[n0 + nn*16 + l15];
        }
        f32x4 acc[4][2];
        #pragma unroll
        for (int m = 0; m < 4; ++m)
            #pragma unroll
            for (int nn = 0; nn < 2; ++nn) acc[m][nn] = (f32x4){0.f,0.f,0.f,0.f};
        #pragma unroll
        for (int m = 0; m < 4; ++m) {
            bf16x8 a[4];
            #pragma unroll
            for (int k = 0; k < 4; ++k)
                a[k] = ldbf8(&RA[(m*16 + l15)*LDA + k*32 + lg*8]);
            #pragma unroll
            for (int k = 0; k < 4; ++k)
                #pragma unroll
                for (int nn = 0; nn < 2; ++nn)
                    acc[m][nn] = __builtin_amdgcn_mfma_f32_16x16x32_bf16(a[k], bo[nn][k], acc[m][nn], 0, 0, 0);
        }
        // XB != RA: no interior barrier needed (delta 1)
        #pragma unroll
        for (int m = 0; m < 4; ++m)
            #pragma unroll
            for (int nn = 0; nn < 2; ++nn)
                #pragma unroll
                for (int j = 0; j < 4; ++j) {
                    int row = m*16 + lg*4 + j;
                    float v = xr[m][nn][j] + gm[nn] * (acc[m][nn][j] + cv[nn]);
                    x1v[m][nn][j] = v;
                    XB[row*LDA + n0 + nn*16 + l15] = f2bf(v);
                }
    }
    __syncthreads();   // B4: x1 bf16 in XB complete

    // ---- P7: LN2 on XB in place ----
    {
        int s = tid >> 2, c = tid & 3;
        float sum = 0.f, sq = 0.f;
        #pragma unroll
        for (int jj = 0; jj < 8; ++jj) {
            s16x4 hv = *(const s16x4*)&XB[s*LDA + c*32 + jj*4];
            #pragma unroll
            for (int e = 0; e < 4; ++e) {
                float f = bf2f(hv[e]);
                sum += f; sq += f*f;
            }
        }
        sum += __shfl_xor(sum, 1); sq += __shfl_xor(sq, 1);
        sum += __shfl_xor(sum, 2); sq += __shfl_xor(sq, 2);
        float mean = sum * (1.f/128.f);
        float var  = sq * (1.f/128.f) - mean*mean;
        float rinv = rsqrtf(var + 1e-5f);
        #pragma unroll
        for (int jj = 0; jj < 8; ++jj) {
            s16x4 hv = *(const s16x4*)&XB[s*LDA + c*32 + jj*4];
            s16x4 ov;
            #pragma unroll
            for (int e = 0; e < 4; ++e) ov[e] = f2bf((bf2f(hv[e]) - mean) * rinv);
            *(s16x4*)&XB[s*LDA + c*32 + jj*4] = ov;
        }
    }
    __syncthreads();   // B5: h2 in XB

    // ---- P8: t1 = gelu(h2 @ W1 + b1) -> RA directly (delta 2) ----
    {
        const short* W1t = wsS + W1T_OFF;
        bf16x8 bw[2][4];
        #pragma unroll
        for (int nn = 0; nn < 2; ++nn)
            #pragma unroll
            for (int k = 0; k < 4; ++k)
                bw[nn][k] = ldbf8(&W1t[(n0 + nn*16 + l15)*128 + k*32 + lg*8]);
        float bb[2];
        #pragma unroll
        for (int nn = 0; nn < 2; ++nn) bb[nn] = b1[n0 + nn*16 + l15];
        #pragma unroll
        for (int m = 0; m < 4; ++m) {
            bf16x8 a[4];
            #pragma unroll
            for (int k = 0; k < 4; ++k)
                a[k] = ldbf8(&XB[(m*16 + l15)*LDA + k*32 + lg*8]);
            #pragma unroll
            for (int nn = 0; nn < 2; ++nn) {
                f32x4 acc = {0.f,0.f,0.f,0.f};
                #pragma unroll
                for (int k = 0; k < 4; ++k)
                    acc = __builtin_amdgcn_mfma_f32_16x16x32_bf16(a[k], bw[nn][k], acc, 0, 0, 0);
                #pragma unroll
                for (int j = 0; j < 4; ++j) {
                    float t = acc[j] + bb[nn];
                    float u = 0.7978845608028654f * (t + 0.044715f*t*t*t);
                    u = fminf(fmaxf(u, -15.f), 15.f);
                    float e = __expf(2.f * u);
                    float g = 0.5f * t * (1.f + (e - 1.f) / (e + 1.f));
                    RA[(m*16 + lg*4 + j)*LDA + n0 + nn*16 + l15] = f2bf(g);
                }
            }
        }
    }
    __syncthreads();   // B6: t1 in RA

    // ---- P9: m = t1 @ W2 + b2 ; out = x1(reg) + gmlp*m (single global write) ----
    {
        const short* W2t = wsS + W2T_OFF;
        const float gmv = gmlp_p[0];
        bf16x8 bw[2][4];
        #pragma unroll
        for (int nn = 0; nn < 2; ++nn)
            #pragma unroll
            for (int k = 0; k < 4; ++k)
                bw[nn][k] = ldbf8(&W2t[(n0 + nn*16 + l15)*128 + k*32 + lg*8]);
        float bb[2];
        #pragma unroll
        for (int nn = 0; nn < 2; ++nn) bb[nn] = b2[n0 + nn*16 + l15];
        #pragma unroll
        for (int m = 0; m < 4; ++m) {
            bf16x8 a[4];
            #pragma unroll
            for (int k = 0; k < 4; ++k)
                a[k] = ldbf8(&RA[(m*16 + l15)*LDA + k*32 + lg*8]);
            #pragma unroll
            for (int nn = 0; nn < 2; ++nn) {
                f32x4 acc = {0.f,0.f,0.f,0.f};
                #pragma unroll
                for (int k = 0; k < 4; ++k)
                    acc = __builtin_amdgcn_mfma_f32_16x16x32_bf16(a[k], bw[nn][k], acc, 0, 0, 0);
                #pragma unroll
                for (int j = 0; j < 4; ++j)
                    outw[(m*16 + lg*4 + j)*128 + n0 + nn*16 + l15] =
                        x1v[m][nn][j] + gmv * (acc[j] + bb[nn]);
            }
        }
    }
}

extern "C" void kernel_launch(void* const* d_in, const int* in_sizes, int n_in,
                              void* d_out, int out_size, void* d_ws, size_t ws_size,
                              hipStream_t stream) {
    const float* x     = (const float*)d_in[0];
    const float* Wq_u  = (const float*)d_in[1];
    const float* Wq_v  = (const float*)d_in[2];
    const float* Wkv_u = (const float*)d_in[3];
    const float* Wkv_v = (const float*)d_in[4];
    const float* kv_b  = (const float*)d_in[5];
    const float* Wo_u  = (const float*)d_in[6];
    const float* Wo_v  = (const float*)d_in[7];
    const float* gamma = (const float*)d_in[8];
    const float* W1    = (const float*)d_in[9];
    const float* b1    = (const float*)d_in[10];
    const float* W2    = (const float*)d_in[11];
    const float* b2    = (const float*)d_in[12];
    const float* gmlp  = (const float*)d_in[13];
    short* wsS  = (short*)d_ws;
    float* cvec = (float*)((char*)d_ws + CVEC_BYTE);
    float* out  = (float*)d_out;

    fam_pre<<<49, 256, 0, stream>>>(Wq_u, Wq_v, Wkv_u, Wkv_v, kv_b, Wo_u, Wo_v, W1, W2, wsS, cvec);
    fam_main<<<NWIN, 256, 0, stream>>>(x, wsS, cvec, gamma, b1, b2, gmlp, out);
}